// Round 6
// baseline (203.975 us; speedup 1.0000x reference)
//
#include <hip/hip_runtime.h>

#define IN_F 512
#define OUT_F 1024
#define K_ACTIVE 11  // ceil(0.01 * 1024) serial MP steps
#define K_IN 6       // ceil(0.01 * 512) kwta winners

// ---- transpose + widen: w [1024][512] f32 -> wTd [513][1024] f64 ----
__global__ __launch_bounds__(256) void transpose_wd_kernel(const float* __restrict__ w,
                                                           double* __restrict__ wTd) {
    __shared__ float tile[32][33];
    const int tx = threadIdx.x & 31;
    const int ty = threadIdx.x >> 5;  // 0..7
    const int i0 = blockIdx.x * 32;
    const int j0 = blockIdx.y * 32;
#pragma unroll
    for (int k = 0; k < 4; ++k)
        tile[ty + 8 * k][tx] = w[(size_t)(j0 + ty + 8 * k) * IN_F + (i0 + tx)];
    __syncthreads();
#pragma unroll
    for (int k = 0; k < 4; ++k)
        wTd[(size_t)(i0 + ty + 8 * k) * OUT_F + (j0 + tx)] = (double)tile[tx][ty + 8 * k];
}
__global__ void zero_row_d_kernel(double* __restrict__ wTd) {
    wTd[(size_t)IN_F * OUT_F + blockIdx.x * 256 + threadIdx.x] = 0.0;
}

// ---- f32 fallback: w -> wT [513][1024] f32 (row 512 zeros) ----
__global__ __launch_bounds__(256) void transpose_w_kernel(const float* __restrict__ w,
                                                          float* __restrict__ wT) {
    __shared__ float tile[32][33];
    const int tx = threadIdx.x & 31;
    const int ty = threadIdx.x >> 5;
    const int i0 = blockIdx.x * 32;
    const int j0 = blockIdx.y * 32;
#pragma unroll
    for (int k = 0; k < 4; ++k)
        tile[ty + 8 * k][tx] = w[(size_t)(j0 + ty + 8 * k) * IN_F + (i0 + tx)];
    __syncthreads();
#pragma unroll
    for (int k = 0; k < 4; ++k)
        wT[(size_t)(i0 + ty + 8 * k) * OUT_F + (j0 + tx)] = tile[tx][ty + 8 * k];
}
__global__ void zero_row_f_kernel(float* __restrict__ wT) {
    wT[(size_t)IN_F * OUT_F + blockIdx.x * 256 + threadIdx.x] = 0.0f;
}

// ---- order-preserving fp64 -> u64 key, low bits carry reversed index ----
__device__ __forceinline__ unsigned long long pack_key(double v, unsigned rev,
                                                       unsigned long long mask) {
    unsigned long long b = (unsigned long long)__double_as_longlong(v);
    unsigned long long m =
        (unsigned long long)((long long)b >> 63) | 0x8000000000000000ull;
    unsigned long long u = b ^ m;  // monotonic total order
    return (u & ~mask) | (unsigned long long)rev;
}

// ---- wave max of u32 via DPP chain (bound_ctrl: invalid lanes -> 0 = identity) ----
template <int C>
__device__ __forceinline__ unsigned maxdpp(unsigned v) {
    unsigned t = (unsigned)__builtin_amdgcn_update_dpp(0, (int)v, C, 0xF, 0xF, true);
    return t > v ? t : v;
}
__device__ __forceinline__ unsigned wave_umax(unsigned v) {
    v = maxdpp<0x111>(v);  // row_shr:1
    v = maxdpp<0x112>(v);  // row_shr:2
    v = maxdpp<0x114>(v);  // row_shr:4
    v = maxdpp<0x118>(v);  // row_shr:8
    v = maxdpp<0x142>(v);  // row_bcast:15
    v = maxdpp<0x143>(v);  // row_bcast:31 -> lane 63 holds wave max
    return (unsigned)__builtin_amdgcn_readlane((int)v, 63);
}

// ---- exact wave max of u64 key: high32 chain + tie resolve (rare path exact) ----
__device__ __forceinline__ unsigned long long wave_max_key(unsigned long long k) {
    const unsigned h = (unsigned)(k >> 32), l = (unsigned)k;
    const unsigned gh = wave_umax(h);
    const unsigned long long tied = __ballot(h == gh);  // uniform
    unsigned gl;
    if (__popcll(tied) == 1) {  // scalar branch, overwhelmingly common
        gl = (unsigned)__builtin_amdgcn_readlane((int)l,
                                                 (int)__ffsll((long long)tied) - 1);
    } else {  // exact: max of low32 among tied lanes
        gl = wave_umax((h == gh) ? l : 0u);
    }
    return ((unsigned long long)gh << 32) | gl;
}

// r[s] += sgn * row_i[j(s)], j = wv*512 + c*256 + lane*4 + e, s = 4c+e.
template <int MODE>
__device__ __forceinline__ void row_axpy(double* r, const double* __restrict__ wTd,
                                         const float* __restrict__ wT,
                                         const float* __restrict__ w, int i,
                                         double sgn, int lane, int wv) {
    if constexpr (MODE == 2) {
        const double* rp = wTd + ((size_t)i << 10) + (wv << 9) + (lane << 2);
#pragma unroll
        for (int c = 0; c < 2; ++c) {
            const double2 a = *(const double2*)(rp + (c << 8));
            const double2 b = *(const double2*)(rp + (c << 8) + 2);
            r[4 * c + 0] += sgn * a.x;
            r[4 * c + 1] += sgn * a.y;
            r[4 * c + 2] += sgn * b.x;
            r[4 * c + 3] += sgn * b.y;
        }
    } else if constexpr (MODE == 1) {
        const float* rp = wT + ((size_t)i << 10) + (wv << 9) + (lane << 2);
#pragma unroll
        for (int c = 0; c < 2; ++c) {
            const float4 f = *(const float4*)(rp + (c << 8));
            r[4 * c + 0] += sgn * (double)f.x;
            r[4 * c + 1] += sgn * (double)f.y;
            r[4 * c + 2] += sgn * (double)f.z;
            r[4 * c + 3] += sgn * (double)f.w;
        }
    } else {
#pragma unroll
        for (int s = 0; s < 8; ++s) {
            int j = (wv << 9) | ((s >> 2) << 8) | (lane << 2) | (s & 3);
            r[s] += sgn * (double)w[(size_t)j * IN_F + i];
        }
    }
}

// paired add (sgn=+1) for the initial projection: 2 rows in flight
template <int MODE>
__device__ __forceinline__ void row_add2(double* r, const double* __restrict__ wTd,
                                         const float* __restrict__ wT, int i0, int i1,
                                         int lane, int wv) {
    if constexpr (MODE == 2) {
        const double* p0 = wTd + ((size_t)i0 << 10) + (wv << 9) + (lane << 2);
        const double* p1 = wTd + ((size_t)i1 << 10) + (wv << 9) + (lane << 2);
        const double2 a0 = *(const double2*)(p0);
        const double2 a1 = *(const double2*)(p0 + 2);
        const double2 a2 = *(const double2*)(p0 + 256);
        const double2 a3 = *(const double2*)(p0 + 258);
        const double2 b0 = *(const double2*)(p1);
        const double2 b1 = *(const double2*)(p1 + 2);
        const double2 b2 = *(const double2*)(p1 + 256);
        const double2 b3 = *(const double2*)(p1 + 258);
        r[0] += a0.x + b0.x;  r[1] += a0.y + b0.y;
        r[2] += a1.x + b1.x;  r[3] += a1.y + b1.y;
        r[4] += a2.x + b2.x;  r[5] += a2.y + b2.y;
        r[6] += a3.x + b3.x;  r[7] += a3.y + b3.y;
    } else {
        const float* p0 = wT + ((size_t)i0 << 10) + (wv << 9) + (lane << 2);
        const float* p1 = wT + ((size_t)i1 << 10) + (wv << 9) + (lane << 2);
        const float4 f0 = *(const float4*)(p0);
        const float4 f1 = *(const float4*)(p0 + 256);
        const float4 g0 = *(const float4*)(p1);
        const float4 g1 = *(const float4*)(p1 + 256);
        r[0] += (double)f0.x + (double)g0.x;  r[1] += (double)f0.y + (double)g0.y;
        r[2] += (double)f0.z + (double)g0.z;  r[3] += (double)f0.w + (double)g0.w;
        r[4] += (double)f1.x + (double)g1.x;  r[5] += (double)f1.y + (double)g1.y;
        r[6] += (double)f1.z + (double)g1.z;  r[7] += (double)f1.w + (double)g1.w;
    }
}

// 2 waves per row: wave wv owns OUT j in [wv*512, (wv+1)*512) (r[8]) and IN i in
// [wv*256, (wv+1)*256) (vd[4]). Persistent fp64 state ~30 VGPR -> fits the
// allocator's 64-VGPR/8-waves-per-EU target with no scratch (verified R5).
template <int MODE>
__global__ __launch_bounds__(128) void bmp_kernel(const float* __restrict__ x,
                                                  const float* __restrict__ w,
                                                  const float* __restrict__ wT,
                                                  const double* __restrict__ wTd,
                                                  float* __restrict__ out, int rows) {
    __shared__ unsigned short act[IN_F + 8];
    __shared__ unsigned long long kx[4];  // parity-double-buffered reduction slots
    const int lane = threadIdx.x & 63;
    const int wv = threadIdx.x >> 6;
    const int row = blockIdx.x;
    if (row >= rows) return;

    // ---- compacted active list of x row (both waves same ballots; wv0 writes) ----
    const float* xrow = x + (size_t)row * IN_F;
    int cnt = 0;
#pragma unroll
    for (int c = 0; c < IN_F / 64; ++c) {
        bool pbit = xrow[c * 64 + lane] != 0.0f;
        unsigned long long m = __ballot(pbit);
        int pre = __popcll(m & ((1ull << lane) - 1ull));
        if (wv == 0 && pbit) act[cnt + pre] = (unsigned short)(c * 64 + lane);
        cnt += __popcll(m);
    }
    if (wv == 0 && lane < 2) act[cnt + lane] = (unsigned short)IN_F;  // zero-row pad
    __syncthreads();

    int rc = 0;  // reduction counter (identical across block)
    auto block_max = [&](unsigned long long k) -> unsigned long long {
        const unsigned long long wm = wave_max_key(k);  // uniform within wave
        if (lane == 0) kx[((rc & 1) << 1) | wv] = wm;
        __syncthreads();
        const unsigned long long a = kx[(rc & 1) << 1];
        const unsigned long long b = kx[((rc & 1) << 1) | 1];
        ++rc;
        return a > b ? a : b;
    };

    // ---- r = 2 * x @ wT (half-row per wave, fp64; maintained incrementally) ----
    double r[8];
#pragma unroll
    for (int s = 0; s < 8; ++s) r[s] = 0.0;
    if constexpr (MODE >= 1) {
#pragma unroll 1
        for (int k = 0; k < cnt; k += 2) {  // act padded with zero-row index
            const int i0 = act[k], i1 = act[k + 1];
            row_add2<MODE>(r, wTd, wT, i0, i1, lane, wv);
        }
    } else {
#pragma unroll 1
        for (int k = 0; k < cnt; ++k) row_axpy<0>(r, wTd, wT, w, act[k], 1.0, lane, wv);
    }
#pragma unroll
    for (int s = 0; s < 8; ++s) r[s] *= 2.0;

    double vd[4];  // quarter of v = encoded @ W: i = wv*256 + lane*4 + p
#pragma unroll
    for (int p = 0; p < 4; ++p) vd[p] = 0.0;

    unsigned enc = 0;      // per-lane 8-bit slot mask over this wave's OUT slots
    unsigned selmask = 0;  // per-lane 4-bit mask of final xr slots
    int O0 = -1, O1 = -1, O2 = -1, O3 = -1, O4 = -1, O5 = -1;  // xr set (uniform)

#pragma unroll 1
    for (int t = 0; t < K_ACTIVE; ++t) {
        // ---- argmax of residual over non-encoded j (lambd >> |dot| => exclusion) ----
        unsigned long long kb = 0;
#pragma unroll
        for (int s = 0; s < 8; ++s) {
            int j = (wv << 9) | ((s >> 2) << 8) | (lane << 2) | (s & 3);
            unsigned long long key = pack_key(r[s], 1023u ^ (unsigned)j, 1023ull);
            key = (enc & (1u << s)) ? 0ull : key;
            kb = key > kb ? key : kb;
        }
        const unsigned long long g = block_max(kb);
        const int bestj =
            __builtin_amdgcn_readfirstlane(1023 ^ (int)(g & 1023ull));  // uniform
        if ((bestj >> 9) == wv && ((bestj >> 2) & 63) == lane)
            enc |= 1u << ((((bestj >> 8) & 1) << 2) | (bestj & 3));

        // ---- v += W[bestj][:] (one 1KB-contiguous float4 load per wave) ----
        {
            const float* wr = w + ((size_t)bestj << 9) + (wv << 8) + (lane << 2);
            const float4 f = *(const float4*)wr;
            vd[0] += (double)f.x;
            vd[1] += (double)f.y;
            vd[2] += (double)f.z;
            vd[3] += (double)f.w;
        }

        // ---- kwta: top-6 of v via 6 packed-key block max-reductions ----
        int N[6];
        {
            unsigned long long vkey[4];  // transient
#pragma unroll
            for (int p = 0; p < 4; ++p) {
                int i = (wv << 8) | (lane << 2) | p;
                vkey[p] = pack_key(vd[p], 511u ^ (unsigned)i, 511ull);
            }
#pragma unroll
            for (int s2 = 0; s2 < K_IN; ++s2) {
                unsigned long long lk = vkey[0];
#pragma unroll
                for (int p = 1; p < 4; ++p) lk = vkey[p] > lk ? vkey[p] : lk;
                const unsigned long long gk = block_max(lk);
                N[s2] = __builtin_amdgcn_readfirstlane(511 ^ (int)(gk & 511ull));
#pragma unroll
                for (int p = 0; p < 4; ++p) vkey[p] = (vkey[p] == gk) ? 0ull : vkey[p];
            }
            if (t == K_ACTIVE - 1) {
                selmask = 0;
#pragma unroll
                for (int p = 0; p < 4; ++p) selmask |= (vkey[p] == 0ull) ? (1u << p) : 0u;
            }
        }

        // ---- incremental residual update: set-diff of xr (uniform logic) ----
        if (t == 0) {
#pragma unroll
            for (int b = 0; b < 6; ++b)
                row_axpy<MODE>(r, wTd, wT, w, N[b], -1.0, lane, wv);
        } else if (t < K_ACTIVE - 1) {
#pragma unroll
            for (int a = 0; a < 6; ++a) {
                const int o = (a == 0) ? O0 : (a == 1) ? O1 : (a == 2) ? O2
                              : (a == 3) ? O3 : (a == 4) ? O4 : O5;
                const bool stay = (o == N[0]) | (o == N[1]) | (o == N[2]) |
                                  (o == N[3]) | (o == N[4]) | (o == N[5]);
                if (!stay) row_axpy<MODE>(r, wTd, wT, w, o, 1.0, lane, wv);
            }
#pragma unroll
            for (int b = 0; b < 6; ++b) {
                const int n = N[b];
                const bool was = (n == O0) | (n == O1) | (n == O2) |
                                 (n == O3) | (n == O4) | (n == O5);
                if (!was) row_axpy<MODE>(r, wTd, wT, w, n, -1.0, lane, wv);
            }
        }
        O0 = N[0]; O1 = N[1]; O2 = N[2]; O3 = N[3]; O4 = N[4]; O5 = N[5];
    }

    // ---- outputs: encoded [rows][OUT_F] then xr [rows][IN_F], coalesced float4 ----
    float* oe = out + (size_t)row * OUT_F + (wv << 9) + (lane << 2);
#pragma unroll
    for (int c = 0; c < 2; ++c) {
        float4 v;
        v.x = (enc & (1u << (4 * c + 0))) ? 1.0f : 0.0f;
        v.y = (enc & (1u << (4 * c + 1))) ? 1.0f : 0.0f;
        v.z = (enc & (1u << (4 * c + 2))) ? 1.0f : 0.0f;
        v.w = (enc & (1u << (4 * c + 3))) ? 1.0f : 0.0f;
        *(float4*)(oe + (c << 8)) = v;
    }
    float* ox = out + (size_t)rows * OUT_F + (size_t)row * IN_F + (wv << 8) + (lane << 2);
    {
        float4 v;
        v.x = (selmask & 1u) ? 1.0f : 0.0f;
        v.y = (selmask & 2u) ? 1.0f : 0.0f;
        v.z = (selmask & 4u) ? 1.0f : 0.0f;
        v.w = (selmask & 8u) ? 1.0f : 0.0f;
        *(float4*)ox = v;
    }
}

extern "C" void kernel_launch(void* const* d_in, const int* in_sizes, int n_in,
                              void* d_out, int out_size, void* d_ws, size_t ws_size,
                              hipStream_t stream) {
    const float* x = (const float*)d_in[0];
    const float* w = (const float*)d_in[1];
    float* out = (float*)d_out;
    const int rows = in_sizes[0] / IN_F;  // 4096

    const size_t need_d = (size_t)(IN_F + 1) * OUT_F * sizeof(double);  // 4.2 MB
    const size_t need_f = (size_t)(IN_F + 1) * OUT_F * sizeof(float);   // 2.1 MB

    if (d_ws != nullptr && ws_size >= need_d) {
        double* wTd = (double*)d_ws;
        transpose_wd_kernel<<<dim3(IN_F / 32, OUT_F / 32), 256, 0, stream>>>(w, wTd);
        zero_row_d_kernel<<<OUT_F / 256, 256, 0, stream>>>(wTd);
        bmp_kernel<2><<<rows, 128, 0, stream>>>(x, w, nullptr, wTd, out, rows);
    } else if (d_ws != nullptr && ws_size >= need_f) {
        float* wT = (float*)d_ws;
        transpose_w_kernel<<<dim3(IN_F / 32, OUT_F / 32), 256, 0, stream>>>(w, wT);
        zero_row_f_kernel<<<OUT_F / 256, 256, 0, stream>>>(wT);
        bmp_kernel<1><<<rows, 128, 0, stream>>>(x, w, wT, nullptr, out, rows);
    } else {
        bmp_kernel<0><<<rows, 128, 0, stream>>>(x, w, nullptr, nullptr, out, rows);
    }
}